// Round 12
// baseline (237.028 us; speedup 1.0000x reference)
//
#include <hip/hip_runtime.h>
#include <hip/hip_bf16.h>

typedef unsigned short ushort_t;
typedef unsigned int uint_t;

typedef __attribute__((ext_vector_type(8))) short bf8;
typedef __attribute__((ext_vector_type(4))) float f4;
typedef __attribute__((ext_vector_type(16))) float f16v;

__device__ __forceinline__ float bf2f(ushort_t u) {
    unsigned int x = ((unsigned int)u) << 16;
    return __uint_as_float(x);
}
__device__ __forceinline__ ushort_t f2bf(float f) {
    unsigned int x = __float_as_uint(f);
    unsigned int r = x + 0x7fffu + ((x >> 16) & 1u);
    return (ushort_t)(r >> 16);
}
__device__ __forceinline__ uint_t pack2bf(float a, float b) {
    return (uint_t)f2bf(a) | ((uint_t)f2bf(b) << 16);
}
// fast pack: round-half-up + v_perm_b32 byte gather (3 VALU vs ~9)
__device__ __forceinline__ uint_t pack2bf_fast(float a, float b) {
    uint_t au = __float_as_uint(a) + 0x8000u;
    uint_t bu = __float_as_uint(b) + 0x8000u;
    return __builtin_amdgcn_perm(bu, au, 0x07060302);  // lo16=a_hi, hi16=b_hi
}
// v_exp_f32 computes 2^x directly (inputs pre-scaled by log2e at QKV time)
__device__ __forceinline__ float exp2_fast(float x) {
    float r; asm("v_exp_f32 %0, %1" : "=v"(r) : "v"(x)); return r;
}
// 2 f32 -> packed bf16 (RTNE), 1 instr vs 3
__device__ __forceinline__ uint_t cvtpk_bf16(float lo, float hi) {
    uint_t r; asm("v_cvt_pk_bf16_f32 %0, %1, %2" : "=v"(r) : "v"(lo), "v"(hi)); return r;
}
// after: a = [a.lo32, b.lo32], b = [a.hi32, b.hi32]
__device__ __forceinline__ void pl32swap(uint_t &a, uint_t &b) {
    asm("v_permlane32_swap_b32 %0, %1" : "+v"(a), "+v"(b));
}

__device__ __forceinline__ void gl2lds16(const ushort_t* g, ushort_t* l) {
    __builtin_amdgcn_global_load_lds(
        (const __attribute__((address_space(1))) void*)g,
        (__attribute__((address_space(3))) void*)l, 16, 0, 0);
}

__device__ __forceinline__ void waitl0() {
    asm volatile("s_waitcnt lgkmcnt(0)" ::: "memory");
    __builtin_amdgcn_sched_barrier(0);
}

// ---------------------------------------------------------------------------
// prep (merged): [0,4096) x fp32->bf16; [4096,4224) Wg pack; [4224,8320)
// weight transpose-convert (4 matrices, 32x32 tiles)
// ---------------------------------------------------------------------------
__global__ __launch_bounds__(256)
void prep(const float* __restrict__ x, ushort_t* __restrict__ xb,
          const float* __restrict__ Wr, const float* __restrict__ Ws,
          ushort_t* __restrict__ Wg,
          const float* __restrict__ W0, const float* __restrict__ W1,
          const float* __restrict__ W2, const float* __restrict__ W3,
          ushort_t* __restrict__ T0, ushort_t* __restrict__ T1,
          ushort_t* __restrict__ T2, ushort_t* __restrict__ T3)
{
    __shared__ float tile[32][33];
    int bid = blockIdx.x;
    int t = threadIdx.x;
    if (bid < 4096) {
        int i = bid * 256 + t;
        float4 v = ((const float4*)x)[i];
        uint2 o;
        o.x = pack2bf(v.x, v.y);
        o.y = pack2bf(v.z, v.w);
        ((uint2*)xb)[i] = o;
    } else if (bid < 4224) {
        int idx = (bid - 4096) * 256 + t;   // 32 x 1024
        int c = idx >> 10, d = idx & 1023;
        float v = 0.f;
        if (c < 15) v = Wr[(size_t)d * 15 + c];
        else if (c < 17) v = Ws[(size_t)d * 2 + (c - 15)];
        Wg[idx] = f2bf(v);
    } else {
        int idx = bid - 4224;               // 4 x 32 x 32 tiles
        int z = idx >> 10, r10 = idx & 1023;
        int k0 = (r10 & 31) * 32, n0 = (r10 >> 5) * 32;
        const float* W; ushort_t* T;
        switch (z) {
            case 0: W = W0; T = T0; break;
            case 1: W = W1; T = T1; break;
            case 2: W = W2; T = T2; break;
            default: W = W3; T = T3; break;
        }
        int r = t >> 3, c4 = (t & 7) * 4;
        float4 v = *(const float4*)&W[(size_t)(k0 + r) * 1024 + n0 + c4];
        tile[r][c4 + 0] = v.x; tile[r][c4 + 1] = v.y;
        tile[r][c4 + 2] = v.z; tile[r][c4 + 3] = v.w;
        __syncthreads();
        int n = t >> 3, kk = (t & 7) * 4;
        uint2 o;
        o.x = pack2bf(tile[kk][n], tile[kk + 1][n]);
        o.y = pack2bf(tile[kk + 2][n], tile[kk + 3][n]);
        *(uint2*)&T[(size_t)(n0 + n) * 1024 + k0 + kk] = o;
    }
}

// ---------------------------------------------------------------------------
// Fused QKV GEMM v10 (proven R11): 128x64 tile, grid (32,48), 4 blocks/CU.
// BK=64, 2-barrier, both-sides XOR swizzle. Unchanged.
// ---------------------------------------------------------------------------
__global__ __launch_bounds__(256)
void gemmQKV(const ushort_t* __restrict__ A, const ushort_t* __restrict__ Wt3,
             const float* __restrict__ bq, const float* __restrict__ bk,
             const float* __restrict__ bv,
             ushort_t* __restrict__ Qb, ushort_t* __restrict__ Kw,
             ushort_t* __restrict__ VTw,
             const float* __restrict__ temp, const float* __restrict__ emb)
{
    const int K = 1024;
    __shared__ ushort_t As[128 * 64];   // 16 KB
    __shared__ ushort_t Bs[64 * 64];    //  8 KB

    int t = threadIdx.x;
    int m0 = blockIdx.x * 128;
    int y = blockIdx.y;                 // 48 tiles of 64 cols
    int region = y >> 4;                // 0=Q 1=K 2=V
    int n0r = (y & 15) * 64;            // col offset within region
    int head = y & 15;

    int lane = t & 63, w = t >> 6;
    int lm = lane & 15, quad = lane >> 4;
    int wm = w * 32;                    // 4 waves stacked in M

    f4 acc[8] = {};   // region2: acc[mi*4+ni]; else (swapped): acc[ni*2+mi]

    int srow = t >> 3;
    int schunk = ((t & 7) ^ (srow & 7)) * 8;
    const ushort_t* pA = &A[(size_t)(m0 + srow) * K + schunk];
    const ushort_t* pB = &Wt3[(size_t)(y * 64 + srow) * K + schunk];
    const size_t rstep = (size_t)32 * K;

    for (int k0 = 0; k0 < K; k0 += 64) {
        #pragma unroll
        for (int j = 0; j < 4; j++)
            gl2lds16(pA + j * rstep, &As[(t + j * 256) * 8]);
        #pragma unroll
        for (int j = 0; j < 2; j++)
            gl2lds16(pB + j * rstep, &Bs[(t + j * 256) * 8]);
        pA += 64; pB += 64;
        __syncthreads();

        #pragma unroll
        for (int ks = 0; ks < 2; ks++) {
            int rc = ((ks * 4 + quad) ^ (lm & 7)) * 8;
            bf8 af[2], bfr[4];
            #pragma unroll
            for (int mi = 0; mi < 2; mi++)
                af[mi] = *(bf8*)&As[(wm + mi * 16 + lm) * 64 + rc];
            #pragma unroll
            for (int ni = 0; ni < 4; ni++)
                bfr[ni] = *(bf8*)&Bs[(ni * 16 + lm) * 64 + rc];
            if (region == 2) {
                #pragma unroll
                for (int mi = 0; mi < 2; mi++)
                #pragma unroll
                for (int ni = 0; ni < 4; ni++)
                    acc[mi * 4 + ni] = __builtin_amdgcn_mfma_f32_16x16x32_bf16(af[mi], bfr[ni], acc[mi * 4 + ni], 0, 0, 0);
            } else {
                #pragma unroll
                for (int ni = 0; ni < 4; ni++)
                #pragma unroll
                for (int mi = 0; mi < 2; mi++)
                    acc[ni * 2 + mi] = __builtin_amdgcn_mfma_f32_16x16x32_bf16(bfr[ni], af[mi], acc[ni * 2 + mi], 0, 0, 0);
            }
        }
        __syncthreads();
    }

    if (region == 0) {
        float sp = log1pf(__expf(temp[head]));
        float qs = sp * 0.18033688011112042f;   // 0.125 * log2(e)
        f4 bv4[4], ev4[4];
        #pragma unroll
        for (int ni = 0; ni < 4; ni++) {
            bv4[ni] = *(const f4*)&bq[n0r + ni * 16 + quad * 4];
            ev4[ni] = *(const f4*)&emb[head * 64 + ni * 16 + quad * 4];
        }
        #pragma unroll
        for (int mi = 0; mi < 2; mi++) {
            float v[4][4];
            float ss = 0.f;
            #pragma unroll
            for (int ni = 0; ni < 4; ni++)
            #pragma unroll
            for (int i = 0; i < 4; i++) {
                v[ni][i] = acc[ni * 2 + mi][i] + bv4[ni][i];
                ss += v[ni][i] * v[ni][i];
            }
            ss += __shfl_xor(ss, 16, 64);
            ss += __shfl_xor(ss, 32, 64);
            float rs = rsqrtf(ss + 1e-12f);
            int tok = m0 + wm + mi * 16 + lm;
            int b = tok >> 11, s = tok & 2047;
            size_t rowb = (((size_t)(b * 16 + head)) * 2048 + s) * 64;
            #pragma unroll
            for (int ni = 0; ni < 4; ni++) {
                uint2 o;
                o.x = pack2bf((v[ni][0] * rs + ev4[ni][0]) * qs,
                              (v[ni][1] * rs + ev4[ni][1]) * qs);
                o.y = pack2bf((v[ni][2] * rs + ev4[ni][2]) * qs,
                              (v[ni][3] * rs + ev4[ni][3]) * qs);
                *(uint2*)&Qb[rowb + ni * 16 + quad * 4] = o;
            }
        }
    } else if (region == 1) {
        f4 bv4[4];
        #pragma unroll
        for (int ni = 0; ni < 4; ni++)
            bv4[ni] = *(const f4*)&bk[n0r + ni * 16 + quad * 4];
        #pragma unroll
        for (int mi = 0; mi < 2; mi++) {
            int tok = m0 + wm + mi * 16 + lm;
            int b = tok >> 11, s = tok & 2047;
            size_t rowb = (((size_t)(b * 16 + head)) * 2048 + s) * 64;
            #pragma unroll
            for (int ni = 0; ni < 4; ni++) {
                uint2 o;
                o.x = pack2bf(acc[ni * 2 + mi][0] + bv4[ni][0], acc[ni * 2 + mi][1] + bv4[ni][1]);
                o.y = pack2bf(acc[ni * 2 + mi][2] + bv4[ni][2], acc[ni * 2 + mi][3] + bv4[ni][3]);
                *(uint2*)&Kw[rowb + ni * 16 + quad * 4] = o;
            }
        }
    } else {
        float bvv[4];
        #pragma unroll
        for (int ni = 0; ni < 4; ni++) bvv[ni] = bv[n0r + ni * 16 + lm];
        #pragma unroll
        for (int mi = 0; mi < 2; mi++) {
            int gr0 = m0 + wm + mi * 16 + quad * 4;
            int b = gr0 >> 11, s0 = gr0 & 2047;
            #pragma unroll
            for (int ni = 0; ni < 4; ni++) {
                int d = ni * 16 + lm;
                uint2 o;
                o.x = pack2bf(acc[mi * 4 + ni][0] + bvv[ni], acc[mi * 4 + ni][1] + bvv[ni]);
                o.y = pack2bf(acc[mi * 4 + ni][2] + bvv[ni], acc[mi * 4 + ni][3] + bvv[ni]);
                *(uint2*)&VTw[(((size_t)(b * 16 + head)) * 64 + d) * 2048 + s0] = o;
            }
        }
    }
}

// ---------------------------------------------------------------------------
// Output projection GEMM v9 (proven R10): 64x128 tile, grid (64,8) = 512
// blocks = 2 blocks/CU. BK=64 + both-sides XOR swizzle. Unchanged.
// ---------------------------------------------------------------------------
__global__ __launch_bounds__(256)
void gemmP(const ushort_t* __restrict__ A, const ushort_t* __restrict__ Wt,
           const float* __restrict__ bias, const float* __restrict__ G,
           float* __restrict__ out, int M, int N, int K)
{
    __shared__ ushort_t As[64 * 64];     //  8 KB
    __shared__ ushort_t Bs[128 * 64];    // 16 KB

    int t = threadIdx.x;
    int m0 = blockIdx.x * 64, n0 = blockIdx.y * 128;
    int lane = t & 63, w = t >> 6;
    int lm = lane & 15, quad = lane >> 4;
    int wm = (w >> 1) * 32, wn = (w & 1) * 64;

    f4 acc[4][2] = {};

    int srow = t >> 3;
    int schunk = ((t & 7) ^ (srow & 7)) * 8;
    const ushort_t* pA = &A[(size_t)(m0 + srow) * K + schunk];
    const ushort_t* pB = &Wt[(size_t)(n0 + srow) * K + schunk];
    const size_t rstep = (size_t)32 * K;

    for (int k0 = 0; k0 < K; k0 += 64) {
        gl2lds16(pA, &As[t * 8]);
        gl2lds16(pA + rstep, &As[(t + 256) * 8]);
        #pragma unroll
        for (int j = 0; j < 4; j++)
            gl2lds16(pB + j * rstep, &Bs[(t + j * 256) * 8]);
        pA += 64; pB += 64;
        __syncthreads();

        #pragma unroll
        for (int ks = 0; ks < 2; ks++) {
            int rc = ((ks * 4 + quad) ^ (lm & 7)) * 8;
            bf8 af[2], bfr[4];
            #pragma unroll
            for (int mi = 0; mi < 2; mi++)
                af[mi] = *(bf8*)&As[(wm + mi * 16 + lm) * 64 + rc];
            #pragma unroll
            for (int ni = 0; ni < 4; ni++)
                bfr[ni] = *(bf8*)&Bs[(wn + ni * 16 + lm) * 64 + rc];
            #pragma unroll
            for (int ni = 0; ni < 4; ni++)
            #pragma unroll
            for (int mi = 0; mi < 2; mi++)
                acc[ni][mi] = __builtin_amdgcn_mfma_f32_16x16x32_bf16(bfr[ni], af[mi], acc[ni][mi], 0, 0, 0);
        }
        __syncthreads();
    }

    f4 bv4[4];
    #pragma unroll
    for (int ni = 0; ni < 4; ni++)
        bv4[ni] = *(const f4*)&bias[n0 + wn + ni * 16 + quad * 4];
    #pragma unroll
    for (int mi = 0; mi < 2; mi++) {
        int tok = m0 + wm + mi * 16 + lm;
        float g = G[tok];
        size_t rowb = (size_t)tok * N + n0 + wn;
        #pragma unroll
        for (int ni = 0; ni < 4; ni++) {
            f4 o;
            #pragma unroll
            for (int i = 0; i < 4; i++) o[i] = g * acc[ni][mi][i] + bv4[ni][i];
            *(f4*)&out[rowb + ni * 16 + quad * 4] = o;
        }
    }
}

// ---------------------------------------------------------------------------
// Flash MFMA attention v11: same proven inner loop, split-K now a runtime
// parameter (kps = keys per split). R11 diagnosis: attn was GRID-limited at
// 4 blocks/CU (VGPR 64 and LDS 18.4KB both allow 8). SK=4 -> grid 2048 ->
// 8 blocks/CU = 32 waves/CU (max). Chosen by launcher iff ws_size fits the
// 32MB Opart + 1MB Lw; else SK=2 (bit-identical to R11).
// ---------------------------------------------------------------------------
__global__ __launch_bounds__(256)
void attn(const ushort_t* __restrict__ Q, const ushort_t* __restrict__ K,
          const ushort_t* __restrict__ VT, ushort_t* __restrict__ Opart,
          float* __restrict__ Lw, int kps)
{
    __shared__ ushort_t Ks[64 * 72];       // [key][dim]
    __shared__ ushort_t Vt[64 * 72];       // [dim][key]

    int t = threadIdx.x, lane = t & 63, w = t >> 6;
    int l31 = lane & 31;
    uint_t hi = lane >> 5;
    int bid = blockIdx.x;
    int bh = bid & 31, qt = (bid >> 5) & 15, ks = bid >> 9;
    size_t base = (size_t)bh * 2048 * 64;

    int tok = qt * 128 + w * 32 + l31;
    const ushort_t* qp = &Q[base + (size_t)tok * 64 + hi * 8];
    bf8 qa[4];
    #pragma unroll
    for (int c = 0; c < 4; c++) qa[c] = *(const bf8*)(qp + c * 16);

    float l_part = 0.f;
    f16v o_acc[2] = {};

    int sr = t >> 3, sc = (t & 7) * 8;
    const ushort_t* kp = &K[base + (size_t)(ks * kps + sr) * 64 + sc];
    const ushort_t* vp = &VT[base + (size_t)sr * 2048 + ks * kps + sc];

    // prologue: load tile 0 into regs
    uint4 rk0 = *(const uint4*)(kp);
    uint4 rk1 = *(const uint4*)(kp + 32 * 64);
    uint4 rv0 = *(const uint4*)(vp);
    uint4 rv1 = *(const uint4*)(vp + 32 * 2048);
    kp += 64 * 64; vp += 64;

    int iters = kps >> 6;
    for (int it = 0; it < iters; ++it) {
        *(uint4*)&Ks[sr * 72 + sc] = rk0;
        *(uint4*)&Ks[(sr + 32) * 72 + sc] = rk1;
        *(uint4*)&Vt[sr * 72 + sc] = rv0;
        *(uint4*)&Vt[(sr + 32) * 72 + sc] = rv1;
        __syncthreads();

        // prefetch next tile; latency hidden under this tile's compute
        rk0 = *(const uint4*)(kp);
        rk1 = *(const uint4*)(kp + 32 * 64);
        rv0 = *(const uint4*)(vp);
        rv1 = *(const uint4*)(vp + 32 * 2048);
        kp += 64 * 64; vp += 64;

        bf8 pf[4];
        #pragma unroll
        for (int kt2 = 0; kt2 < 2; kt2++) {
            f16v s = {};
            #pragma unroll
            for (int c = 0; c < 4; c++) {
                bf8 kf = *(bf8*)&Ks[(kt2 * 32 + l31) * 72 + c * 16 + hi * 8];
                s = __builtin_amdgcn_mfma_f32_32x32x16_bf16(kf, qa[c], s, 0, 0, 0);
            }
            uint_t px[4], py[4];
            #pragma unroll
            for (int g = 0; g < 4; g++) {
                float p0 = exp2_fast(s[g * 4 + 0]);
                float p1 = exp2_fast(s[g * 4 + 1]);
                float p2 = exp2_fast(s[g * 4 + 2]);
                float p3 = exp2_fast(s[g * 4 + 3]);
                l_part += (p0 + p1) + (p2 + p3);
                px[g] = cvtpk_bf16(p0, p1);
                py[g] = cvtpk_bf16(p2, p3);
            }
            #pragma unroll
            for (int cc = 0; cc < 2; cc++) {
                uint_t ax = px[2 * cc], bx = px[2 * cc + 1];
                uint_t ay = py[2 * cc], by = py[2 * cc + 1];
                pl32swap(ax, bx);    // ax = u.x (keys j0..3), bx = u.z (j4..7)
                pl32swap(ay, by);    // ay = u.y,              by = u.w
                uint4 u;
                u.x = ax; u.y = ay; u.z = bx; u.w = by;
                pf[kt2 * 2 + cc] = *(bf8*)&u;
            }
        }

        #pragma unroll
        for (int c = 0; c < 4; c++) {
            #pragma unroll
            for (int dt = 0; dt < 2; dt++) {
                bf8 vf = *(bf8*)&Vt[(dt * 32 + l31) * 72 + c * 16 + hi * 8];
                o_acc[dt] = __builtin_amdgcn_mfma_f32_32x32x16_bf16(vf, pf[c], o_acc[dt], 0, 0, 0);
            }
        }
        __syncthreads();
    }

    l_part += __shfl_xor(l_part, 32, 64);
    if (hi == 0) Lw[((size_t)ks * 32 + bh) * 2048 + tok] = l_part;

    size_t pbase = (((size_t)(ks * 32 + bh)) * 2048 + tok) * 64;
    #pragma unroll
    for (int dt = 0; dt < 2; dt++)
    #pragma unroll
    for (int g = 0; g < 4; g++) {
        int d0 = dt * 32 + g * 8 + hi * 4;
        uint2 o;
        o.x = pack2bf_fast(o_acc[dt][g * 4 + 0], o_acc[dt][g * 4 + 1]);
        o.y = pack2bf_fast(o_acc[dt][g * 4 + 2], o_acc[dt][g * 4 + 3]);
        *(uint2*)&Opart[pbase + d0] = o;
    }
}

// ---------------------------------------------------------------------------
// Fused combine + router, runtime split count. Grid 256 x 256.
// ---------------------------------------------------------------------------
__global__ __launch_bounds__(256)
void fuseCR(const ushort_t* __restrict__ Opart, const float* __restrict__ Lw,
            const ushort_t* __restrict__ Wg, const float* __restrict__ br,
            const float* __restrict__ bs, ushort_t* __restrict__ Ob,
            float* __restrict__ G, int splits)
{
    __shared__ ushort_t Obs[16 * 1032];    // 16 tokens x 1024 dims, +8 pad
    __shared__ float rl_s[16][16];         // [head][token]
    __shared__ float Ls[16][21];

    int t = threadIdx.x;
    int tokg0 = blockIdx.x * 16;
    int b = tokg0 >> 11, st0 = tokg0 & 2047;

    // stage per-(head,token) reciprocal denominators (exactly 256 of them)
    {
        int h = t >> 4, tt = t & 15;
        size_t row = (size_t)(b * 16 + h) * 2048 + st0 + tt;
        float l = 0.f;
        #pragma unroll 4
        for (int s = 0; s < splits; s++) l += Lw[(size_t)s * 65536 + row];
        rl_s[h][tt] = 1.f / l;
    }
    __syncthreads();

    // combine: thread t -> token tt = t>>4, dims dc..dc+3 (uint2 per split)
    {
        int tt = t >> 4, dc = (t & 15) * 4;
        #pragma unroll 4
        for (int h = 0; h < 16; h++) {
            size_t rbase = ((size_t)(b * 16 + h) * 2048 + st0 + tt) * 64 + dc;
            float v0 = 0.f, v1 = 0.f, v2 = 0.f, v3 = 0.f;
            #pragma unroll 4
            for (int s = 0; s < splits; s++) {
                uint2 p = *(const uint2*)&Opart[(size_t)s * 4194304 + rbase];
                v0 += bf2f(p.x & 0xffff);
                v1 += bf2f(p.x >> 16);
                v2 += bf2f(p.y & 0xffff);
                v3 += bf2f(p.y >> 16);
            }
            float rl = rl_s[h][tt];
            v0 *= rl; v1 *= rl; v2 *= rl; v3 *= rl;
            uint2 o;
            o.x = pack2bf(v0, v1);
            o.y = pack2bf(v2, v3);
            *(uint2*)&Obs[tt * 1032 + h * 64 + dc] = o;
            *(uint2*)&Ob[((size_t)(tokg0 + tt)) * 1024 + h * 64 + dc] = o;
        }
    }
    __syncthreads();

    // router (wave 0 only): logits[16 tok][17] from LDS
    if (t < 64) {
        int lm = t & 15, quad = t >> 4;
        const ushort_t* b0p = &Wg[(size_t)lm * 1024 + quad * 8];
        const ushort_t* b1p = &Wg[(size_t)(16 + lm) * 1024 + quad * 8];
        f4 acc0 = {}, acc1 = {};
        for (int k0 = 0; k0 < 1024; k0 += 32) {
            bf8 a  = *(const bf8*)&Obs[lm * 1032 + k0 + quad * 8];
            bf8 b0 = *(const bf8*)(b0p + k0);
            bf8 b1 = *(const bf8*)(b1p + k0);
            acc0 = __builtin_amdgcn_mfma_f32_16x16x32_bf16(a, b0, acc0, 0, 0, 0);
            acc1 = __builtin_amdgcn_mfma_f32_16x16x32_bf16(a, b1, acc1, 0, 0, 0);
        }
        #pragma unroll
        for (int i = 0; i < 4; i++) {
            int tl = quad * 4 + i;
            Ls[tl][lm] = acc0[i];
            if (lm == 0) Ls[tl][16] = acc1[i];
        }
        waitl0();   // intra-wave LDS ordering before cross-lane read

        if (t < 16) {
            float v[15];
            float mx = -1e30f;
            #pragma unroll
            for (int c = 0; c < 15; c++) { v[c] = Ls[t][c] + br[c]; mx = fmaxf(mx, v[c]); }
            float sum = 0.f;
            #pragma unroll
            for (int c = 0; c < 15; c++) { v[c] = __expf(v[c] - mx); sum += v[c]; }
            float inv = 1.f / sum;
            float t3 = 0.f;
            for (int r = 0; r < 3; r++) {
                int bi = 0; float bv = -1e30f;
                #pragma unroll
                for (int c = 0; c < 15; c++) if (v[c] > bv) { bv = v[c]; bi = c; }
                t3 += bv; v[bi] = -1e30f;
            }
            t3 *= inv;
            float a0 = Ls[t][15] + bs[0], a1 = Ls[t][16] + bs[1];
            float m2 = fmaxf(a0, a1);
            float e0 = __expf(a0 - m2), e1 = __expf(a1 - m2);
            G[tokg0 + t] = (2.f * e0 + 6.f * e1 * t3) / (e0 + e1);
        }
    }
}

// ---------------------------------------------------------------------------
extern "C" void kernel_launch(void* const* d_in, const int* in_sizes, int n_in,
                              void* d_out, int out_size, void* d_ws, size_t ws_size,
                              hipStream_t stream)
{
    const float* x     = (const float*)d_in[0];
    const float* Wq    = (const float*)d_in[1];
    const float* bq    = (const float*)d_in[2];
    const float* Wk    = (const float*)d_in[3];
    const float* bk    = (const float*)d_in[4];
    const float* Wv    = (const float*)d_in[5];
    const float* bv    = (const float*)d_in[6];
    const float* Wproj = (const float*)d_in[7];
    const float* bproj = (const float*)d_in[8];
    const float* Wr    = (const float*)d_in[9];
    const float* br    = (const float*)d_in[10];
    const float* Ws    = (const float*)d_in[11];
    const float* bs    = (const float*)d_in[12];
    const float* temp  = (const float*)d_in[13];
    const float* emb   = (const float*)d_in[14];

    const int M = 4096, N = 1024, Kd = 1024;

    char* ws = (char*)d_ws;
    ushort_t* Kw    = (ushort_t*)ws;                    //  8 MB [B,H,S,64]
    ushort_t* VTw   = (ushort_t*)(ws + 8388608);        //  8 MB [B,H,64,S]
    ushort_t* Qb    = (ushort_t*)(ws + 16777216);       //  8 MB Q; Ob after attn
    ushort_t* Wtp   = (ushort_t*)(ws + 25165824);       //  2 MB Wproj^T
    float*    Gw    = (float*)(ws + 27262976);          // 16 KB
    ushort_t* Wg    = (ushort_t*)(ws + 27279360);       // 64 KB
    ushort_t* Wt3   = (ushort_t*)(ws + 27869184);       //  6 MB (dead after QKV)
    ushort_t* Opart = (ushort_t*)(ws + 27869184);       // SK*8 MB, overlays Wt3+xb
    ushort_t* xb    = (ushort_t*)(ws + 34160640);       //  8 MB (dead after QKV)
    ushort_t* Ob    = Qb;                               // fuseCR writes over Q

    // split-K count: 4 if workspace fits Opart 32MB + Lw 1MB, else 2.
    int SK;
    float* Lw;
    if (ws_size >= 62472192) {
        SK = 4;
        Lw = (float*)(ws + 61423616);                   // after 32MB Opart
    } else {
        SK = 2;
        Lw = (float*)(ws + 27344896);                   // legacy 512KB slot
    }

    prep<<<8320, 256, 0, stream>>>(x, xb, Wr, Ws, Wg, Wq, Wk, Wv, Wproj,
        Wt3, Wt3 + 1048576, Wt3 + 2097152, Wtp);

    gemmQKV<<<dim3(32, 48), 256, 0, stream>>>(xb, Wt3, bq, bk, bv,
        Qb, Kw, VTw, temp, emb);

    attn<<<512 * SK, 256, 0, stream>>>(Qb, Kw, VTw, Opart, Lw, 2048 / SK);

    fuseCR<<<256, 256, 0, stream>>>(Opart, Lw, Wg, br, bs, Ob, Gw, SK);

    gemmP<<<dim3(64, 8), 256, 0, stream>>>(Ob, Wtp, bproj, Gw, (float*)d_out, M, N, Kd);
}

// Round 13
// 235.066 us; speedup vs baseline: 1.0083x; 1.0083x over previous
//
#include <hip/hip_runtime.h>
#include <hip/hip_bf16.h>

typedef unsigned short ushort_t;
typedef unsigned int uint_t;

typedef __attribute__((ext_vector_type(8))) short bf8;
typedef __attribute__((ext_vector_type(4))) float f4;
typedef __attribute__((ext_vector_type(16))) float f16v;

__device__ __forceinline__ float bf2f(ushort_t u) {
    unsigned int x = ((unsigned int)u) << 16;
    return __uint_as_float(x);
}
__device__ __forceinline__ ushort_t f2bf(float f) {
    unsigned int x = __float_as_uint(f);
    unsigned int r = x + 0x7fffu + ((x >> 16) & 1u);
    return (ushort_t)(r >> 16);
}
__device__ __forceinline__ uint_t pack2bf(float a, float b) {
    return (uint_t)f2bf(a) | ((uint_t)f2bf(b) << 16);
}
// fast pack: round-half-up + v_perm_b32 byte gather (3 VALU vs ~9)
__device__ __forceinline__ uint_t pack2bf_fast(float a, float b) {
    uint_t au = __float_as_uint(a) + 0x8000u;
    uint_t bu = __float_as_uint(b) + 0x8000u;
    return __builtin_amdgcn_perm(bu, au, 0x07060302);  // lo16=a_hi, hi16=b_hi
}
// v_exp_f32 computes 2^x directly (inputs pre-scaled by log2e at QKV time)
__device__ __forceinline__ float exp2_fast(float x) {
    float r; asm("v_exp_f32 %0, %1" : "=v"(r) : "v"(x)); return r;
}
// 2 f32 -> packed bf16 (RTNE), 1 instr vs 3
__device__ __forceinline__ uint_t cvtpk_bf16(float lo, float hi) {
    uint_t r; asm("v_cvt_pk_bf16_f32 %0, %1, %2" : "=v"(r) : "v"(lo), "v"(hi)); return r;
}
// after: a = [a.lo32, b.lo32], b = [a.hi32, b.hi32]
__device__ __forceinline__ void pl32swap(uint_t &a, uint_t &b) {
    asm("v_permlane32_swap_b32 %0, %1" : "+v"(a), "+v"(b));
}

__device__ __forceinline__ void gl2lds16(const ushort_t* g, ushort_t* l) {
    __builtin_amdgcn_global_load_lds(
        (const __attribute__((address_space(1))) void*)g,
        (__attribute__((address_space(3))) void*)l, 16, 0, 0);
}

__device__ __forceinline__ void waitl0() {
    asm volatile("s_waitcnt lgkmcnt(0)" ::: "memory");
    __builtin_amdgcn_sched_barrier(0);
}

// ---------------------------------------------------------------------------
// prep (merged): [0,4096) x fp32->bf16; [4096,4224) Wg pack; [4224,8320)
// weight transpose-convert (4 matrices, 32x32 tiles)
// ---------------------------------------------------------------------------
__global__ __launch_bounds__(256)
void prep(const float* __restrict__ x, ushort_t* __restrict__ xb,
          const float* __restrict__ Wr, const float* __restrict__ Ws,
          ushort_t* __restrict__ Wg,
          const float* __restrict__ W0, const float* __restrict__ W1,
          const float* __restrict__ W2, const float* __restrict__ W3,
          ushort_t* __restrict__ T0, ushort_t* __restrict__ T1,
          ushort_t* __restrict__ T2, ushort_t* __restrict__ T3)
{
    __shared__ float tile[32][33];
    int bid = blockIdx.x;
    int t = threadIdx.x;
    if (bid < 4096) {
        int i = bid * 256 + t;
        float4 v = ((const float4*)x)[i];
        uint2 o;
        o.x = pack2bf(v.x, v.y);
        o.y = pack2bf(v.z, v.w);
        ((uint2*)xb)[i] = o;
    } else if (bid < 4224) {
        int idx = (bid - 4096) * 256 + t;   // 32 x 1024
        int c = idx >> 10, d = idx & 1023;
        float v = 0.f;
        if (c < 15) v = Wr[(size_t)d * 15 + c];
        else if (c < 17) v = Ws[(size_t)d * 2 + (c - 15)];
        Wg[idx] = f2bf(v);
    } else {
        int idx = bid - 4224;               // 4 x 32 x 32 tiles
        int z = idx >> 10, r10 = idx & 1023;
        int k0 = (r10 & 31) * 32, n0 = (r10 >> 5) * 32;
        const float* W; ushort_t* T;
        switch (z) {
            case 0: W = W0; T = T0; break;
            case 1: W = W1; T = T1; break;
            case 2: W = W2; T = T2; break;
            default: W = W3; T = T3; break;
        }
        int r = t >> 3, c4 = (t & 7) * 4;
        float4 v = *(const float4*)&W[(size_t)(k0 + r) * 1024 + n0 + c4];
        tile[r][c4 + 0] = v.x; tile[r][c4 + 1] = v.y;
        tile[r][c4 + 2] = v.z; tile[r][c4 + 3] = v.w;
        __syncthreads();
        int n = t >> 3, kk = (t & 7) * 4;
        uint2 o;
        o.x = pack2bf(tile[kk][n], tile[kk + 1][n]);
        o.y = pack2bf(tile[kk + 2][n], tile[kk + 3][n]);
        *(uint2*)&T[(size_t)(n0 + n) * 1024 + k0 + kk] = o;
    }
}

// ---------------------------------------------------------------------------
// Fused QKV GEMM v10 (proven R11): 128x64 tile, grid (32,48), 4 blocks/CU.
// BK=64, 2-barrier, both-sides XOR swizzle. Unchanged.
// ---------------------------------------------------------------------------
__global__ __launch_bounds__(256)
void gemmQKV(const ushort_t* __restrict__ A, const ushort_t* __restrict__ Wt3,
             const float* __restrict__ bq, const float* __restrict__ bk,
             const float* __restrict__ bv,
             ushort_t* __restrict__ Qb, ushort_t* __restrict__ Kw,
             ushort_t* __restrict__ VTw,
             const float* __restrict__ temp, const float* __restrict__ emb)
{
    const int K = 1024;
    __shared__ ushort_t As[128 * 64];   // 16 KB
    __shared__ ushort_t Bs[64 * 64];    //  8 KB

    int t = threadIdx.x;
    int m0 = blockIdx.x * 128;
    int y = blockIdx.y;                 // 48 tiles of 64 cols
    int region = y >> 4;                // 0=Q 1=K 2=V
    int n0r = (y & 15) * 64;            // col offset within region
    int head = y & 15;

    int lane = t & 63, w = t >> 6;
    int lm = lane & 15, quad = lane >> 4;
    int wm = w * 32;                    // 4 waves stacked in M

    f4 acc[8] = {};   // region2: acc[mi*4+ni]; else (swapped): acc[ni*2+mi]

    int srow = t >> 3;
    int schunk = ((t & 7) ^ (srow & 7)) * 8;
    const ushort_t* pA = &A[(size_t)(m0 + srow) * K + schunk];
    const ushort_t* pB = &Wt3[(size_t)(y * 64 + srow) * K + schunk];
    const size_t rstep = (size_t)32 * K;

    for (int k0 = 0; k0 < K; k0 += 64) {
        #pragma unroll
        for (int j = 0; j < 4; j++)
            gl2lds16(pA + j * rstep, &As[(t + j * 256) * 8]);
        #pragma unroll
        for (int j = 0; j < 2; j++)
            gl2lds16(pB + j * rstep, &Bs[(t + j * 256) * 8]);
        pA += 64; pB += 64;
        __syncthreads();

        #pragma unroll
        for (int ks = 0; ks < 2; ks++) {
            int rc = ((ks * 4 + quad) ^ (lm & 7)) * 8;
            bf8 af[2], bfr[4];
            #pragma unroll
            for (int mi = 0; mi < 2; mi++)
                af[mi] = *(bf8*)&As[(wm + mi * 16 + lm) * 64 + rc];
            #pragma unroll
            for (int ni = 0; ni < 4; ni++)
                bfr[ni] = *(bf8*)&Bs[(ni * 16 + lm) * 64 + rc];
            if (region == 2) {
                #pragma unroll
                for (int mi = 0; mi < 2; mi++)
                #pragma unroll
                for (int ni = 0; ni < 4; ni++)
                    acc[mi * 4 + ni] = __builtin_amdgcn_mfma_f32_16x16x32_bf16(af[mi], bfr[ni], acc[mi * 4 + ni], 0, 0, 0);
            } else {
                #pragma unroll
                for (int ni = 0; ni < 4; ni++)
                #pragma unroll
                for (int mi = 0; mi < 2; mi++)
                    acc[ni * 2 + mi] = __builtin_amdgcn_mfma_f32_16x16x32_bf16(bfr[ni], af[mi], acc[ni * 2 + mi], 0, 0, 0);
            }
        }
        __syncthreads();
    }

    if (region == 0) {
        float sp = log1pf(__expf(temp[head]));
        float qs = sp * 0.18033688011112042f;   // 0.125 * log2(e)
        f4 bv4[4], ev4[4];
        #pragma unroll
        for (int ni = 0; ni < 4; ni++) {
            bv4[ni] = *(const f4*)&bq[n0r + ni * 16 + quad * 4];
            ev4[ni] = *(const f4*)&emb[head * 64 + ni * 16 + quad * 4];
        }
        #pragma unroll
        for (int mi = 0; mi < 2; mi++) {
            float v[4][4];
            float ss = 0.f;
            #pragma unroll
            for (int ni = 0; ni < 4; ni++)
            #pragma unroll
            for (int i = 0; i < 4; i++) {
                v[ni][i] = acc[ni * 2 + mi][i] + bv4[ni][i];
                ss += v[ni][i] * v[ni][i];
            }
            ss += __shfl_xor(ss, 16, 64);
            ss += __shfl_xor(ss, 32, 64);
            float rs = rsqrtf(ss + 1e-12f);
            int tok = m0 + wm + mi * 16 + lm;
            int b = tok >> 11, s = tok & 2047;
            size_t rowb = (((size_t)(b * 16 + head)) * 2048 + s) * 64;
            #pragma unroll
            for (int ni = 0; ni < 4; ni++) {
                uint2 o;
                o.x = pack2bf((v[ni][0] * rs + ev4[ni][0]) * qs,
                              (v[ni][1] * rs + ev4[ni][1]) * qs);
                o.y = pack2bf((v[ni][2] * rs + ev4[ni][2]) * qs,
                              (v[ni][3] * rs + ev4[ni][3]) * qs);
                *(uint2*)&Qb[rowb + ni * 16 + quad * 4] = o;
            }
        }
    } else if (region == 1) {
        f4 bv4[4];
        #pragma unroll
        for (int ni = 0; ni < 4; ni++)
            bv4[ni] = *(const f4*)&bk[n0r + ni * 16 + quad * 4];
        #pragma unroll
        for (int mi = 0; mi < 2; mi++) {
            int tok = m0 + wm + mi * 16 + lm;
            int b = tok >> 11, s = tok & 2047;
            size_t rowb = (((size_t)(b * 16 + head)) * 2048 + s) * 64;
            #pragma unroll
            for (int ni = 0; ni < 4; ni++) {
                uint2 o;
                o.x = pack2bf(acc[ni * 2 + mi][0] + bv4[ni][0], acc[ni * 2 + mi][1] + bv4[ni][1]);
                o.y = pack2bf(acc[ni * 2 + mi][2] + bv4[ni][2], acc[ni * 2 + mi][3] + bv4[ni][3]);
                *(uint2*)&Kw[rowb + ni * 16 + quad * 4] = o;
            }
        }
    } else {
        float bvv[4];
        #pragma unroll
        for (int ni = 0; ni < 4; ni++) bvv[ni] = bv[n0r + ni * 16 + lm];
        #pragma unroll
        for (int mi = 0; mi < 2; mi++) {
            int gr0 = m0 + wm + mi * 16 + quad * 4;
            int b = gr0 >> 11, s0 = gr0 & 2047;
            #pragma unroll
            for (int ni = 0; ni < 4; ni++) {
                int d = ni * 16 + lm;
                uint2 o;
                o.x = pack2bf(acc[mi * 4 + ni][0] + bvv[ni], acc[mi * 4 + ni][1] + bvv[ni]);
                o.y = pack2bf(acc[mi * 4 + ni][2] + bvv[ni], acc[mi * 4 + ni][3] + bvv[ni]);
                *(uint2*)&VTw[(((size_t)(b * 16 + head)) * 64 + d) * 2048 + s0] = o;
            }
        }
    }
}

// ---------------------------------------------------------------------------
// Output projection GEMM v9 (proven R10): 64x128 tile, grid (64,8) = 512
// blocks = 2 blocks/CU. BK=64 + both-sides XOR swizzle. Unchanged.
// ---------------------------------------------------------------------------
__global__ __launch_bounds__(256)
void gemmP(const ushort_t* __restrict__ A, const ushort_t* __restrict__ Wt,
           const float* __restrict__ bias, const float* __restrict__ G,
           float* __restrict__ out, int M, int N, int K)
{
    __shared__ ushort_t As[64 * 64];     //  8 KB
    __shared__ ushort_t Bs[128 * 64];    // 16 KB

    int t = threadIdx.x;
    int m0 = blockIdx.x * 64, n0 = blockIdx.y * 128;
    int lane = t & 63, w = t >> 6;
    int lm = lane & 15, quad = lane >> 4;
    int wm = (w >> 1) * 32, wn = (w & 1) * 64;

    f4 acc[4][2] = {};

    int srow = t >> 3;
    int schunk = ((t & 7) ^ (srow & 7)) * 8;
    const ushort_t* pA = &A[(size_t)(m0 + srow) * K + schunk];
    const ushort_t* pB = &Wt[(size_t)(n0 + srow) * K + schunk];
    const size_t rstep = (size_t)32 * K;

    for (int k0 = 0; k0 < K; k0 += 64) {
        gl2lds16(pA, &As[t * 8]);
        gl2lds16(pA + rstep, &As[(t + 256) * 8]);
        #pragma unroll
        for (int j = 0; j < 4; j++)
            gl2lds16(pB + j * rstep, &Bs[(t + j * 256) * 8]);
        pA += 64; pB += 64;
        __syncthreads();

        #pragma unroll
        for (int ks = 0; ks < 2; ks++) {
            int rc = ((ks * 4 + quad) ^ (lm & 7)) * 8;
            bf8 af[2], bfr[4];
            #pragma unroll
            for (int mi = 0; mi < 2; mi++)
                af[mi] = *(bf8*)&As[(wm + mi * 16 + lm) * 64 + rc];
            #pragma unroll
            for (int ni = 0; ni < 4; ni++)
                bfr[ni] = *(bf8*)&Bs[(wn + ni * 16 + lm) * 64 + rc];
            #pragma unroll
            for (int ni = 0; ni < 4; ni++)
            #pragma unroll
            for (int mi = 0; mi < 2; mi++)
                acc[ni][mi] = __builtin_amdgcn_mfma_f32_16x16x32_bf16(bfr[ni], af[mi], acc[ni][mi], 0, 0, 0);
        }
        __syncthreads();
    }

    f4 bv4[4];
    #pragma unroll
    for (int ni = 0; ni < 4; ni++)
        bv4[ni] = *(const f4*)&bias[n0 + wn + ni * 16 + quad * 4];
    #pragma unroll
    for (int mi = 0; mi < 2; mi++) {
        int tok = m0 + wm + mi * 16 + lm;
        float g = G[tok];
        size_t rowb = (size_t)tok * N + n0 + wn;
        #pragma unroll
        for (int ni = 0; ni < 4; ni++) {
            f4 o;
            #pragma unroll
            for (int i = 0; i < 4; i++) o[i] = g * acc[ni][mi][i] + bv4[ni][i];
            *(f4*)&out[rowb + ni * 16 + quad * 4] = o;
        }
    }
}

// ---------------------------------------------------------------------------
// Flash MFMA attention v12: K/V LDS DOUBLE-BUFFERED -> 1 barrier per 64-key
// tile (was 2). R12 proved attn is not TLP-limited (SK4: occupancy and time
// unchanged) -> attack the serial chain's fixed overhead instead. Pipeline:
// regs hold tile t+1; per iter: write regs->buf[cur^1], prefetch tile t+2,
// compute from buf[cur], ONE barrier (covers write-visibility of cur^1 AND
// read-drain of cur), swap. Tail prefetch/writes run past the panel into
// mapped workspace and are never consumed. LDS 36.9KB (4 blocks/CU still).
// ---------------------------------------------------------------------------
__global__ __launch_bounds__(256)
void attn(const ushort_t* __restrict__ Q, const ushort_t* __restrict__ K,
          const ushort_t* __restrict__ VT, ushort_t* __restrict__ Opart,
          float* __restrict__ Lw, int kps)
{
    __shared__ ushort_t Ks[2][64 * 72];    // [buf][key][dim]
    __shared__ ushort_t Vt[2][64 * 72];    // [buf][dim][key]

    int t = threadIdx.x, lane = t & 63, w = t >> 6;
    int l31 = lane & 31;
    uint_t hi = lane >> 5;
    int bid = blockIdx.x;
    int bh = bid & 31, qt = (bid >> 5) & 15, ks = bid >> 9;
    size_t base = (size_t)bh * 2048 * 64;

    int tok = qt * 128 + w * 32 + l31;
    const ushort_t* qp = &Q[base + (size_t)tok * 64 + hi * 8];
    bf8 qa[4];
    #pragma unroll
    for (int c = 0; c < 4; c++) qa[c] = *(const bf8*)(qp + c * 16);

    float l_part = 0.f;
    f16v o_acc[2] = {};

    int sr = t >> 3, sc = (t & 7) * 8;
    const ushort_t* kp = &K[base + (size_t)(ks * kps + sr) * 64 + sc];
    const ushort_t* vp = &VT[base + (size_t)sr * 2048 + ks * kps + sc];

    // prologue: tile0 -> regs -> buf0; tile1 -> regs (in flight)
    uint4 rk0 = *(const uint4*)(kp);
    uint4 rk1 = *(const uint4*)(kp + 32 * 64);
    uint4 rv0 = *(const uint4*)(vp);
    uint4 rv1 = *(const uint4*)(vp + 32 * 2048);
    kp += 64 * 64; vp += 64;
    *(uint4*)&Ks[0][sr * 72 + sc] = rk0;
    *(uint4*)&Ks[0][(sr + 32) * 72 + sc] = rk1;
    *(uint4*)&Vt[0][sr * 72 + sc] = rv0;
    *(uint4*)&Vt[0][(sr + 32) * 72 + sc] = rv1;
    rk0 = *(const uint4*)(kp);
    rk1 = *(const uint4*)(kp + 32 * 64);
    rv0 = *(const uint4*)(vp);
    rv1 = *(const uint4*)(vp + 32 * 2048);
    kp += 64 * 64; vp += 64;
    __syncthreads();

    int cur = 0;
    int iters = kps >> 6;
    for (int it = 0; it < iters; ++it) {
        // stage tile it+1 (in regs) into the idle buffer; prefetch tile it+2
        {
            ushort_t* Kw_ = &Ks[cur ^ 1][0];
            ushort_t* Vw_ = &Vt[cur ^ 1][0];
            *(uint4*)&Kw_[sr * 72 + sc] = rk0;
            *(uint4*)&Kw_[(sr + 32) * 72 + sc] = rk1;
            *(uint4*)&Vw_[sr * 72 + sc] = rv0;
            *(uint4*)&Vw_[(sr + 32) * 72 + sc] = rv1;
        }
        rk0 = *(const uint4*)(kp);
        rk1 = *(const uint4*)(kp + 32 * 64);
        rv0 = *(const uint4*)(vp);
        rv1 = *(const uint4*)(vp + 32 * 2048);
        kp += 64 * 64; vp += 64;

        const ushort_t* Kr = &Ks[cur][0];
        const ushort_t* Vr = &Vt[cur][0];

        bf8 pf[4];
        #pragma unroll
        for (int kt2 = 0; kt2 < 2; kt2++) {
            f16v s = {};
            #pragma unroll
            for (int c = 0; c < 4; c++) {
                bf8 kf = *(bf8*)&Kr[(kt2 * 32 + l31) * 72 + c * 16 + hi * 8];
                s = __builtin_amdgcn_mfma_f32_32x32x16_bf16(kf, qa[c], s, 0, 0, 0);
            }
            uint_t px[4], py[4];
            #pragma unroll
            for (int g = 0; g < 4; g++) {
                float p0 = exp2_fast(s[g * 4 + 0]);
                float p1 = exp2_fast(s[g * 4 + 1]);
                float p2 = exp2_fast(s[g * 4 + 2]);
                float p3 = exp2_fast(s[g * 4 + 3]);
                l_part += (p0 + p1) + (p2 + p3);
                px[g] = cvtpk_bf16(p0, p1);
                py[g] = cvtpk_bf16(p2, p3);
            }
            #pragma unroll
            for (int cc = 0; cc < 2; cc++) {
                uint_t ax = px[2 * cc], bx = px[2 * cc + 1];
                uint_t ay = py[2 * cc], by = py[2 * cc + 1];
                pl32swap(ax, bx);    // ax = u.x (keys j0..3), bx = u.z (j4..7)
                pl32swap(ay, by);    // ay = u.y,              by = u.w
                uint4 u;
                u.x = ax; u.y = ay; u.z = bx; u.w = by;
                pf[kt2 * 2 + cc] = *(bf8*)&u;
            }
        }

        #pragma unroll
        for (int c = 0; c < 4; c++) {
            #pragma unroll
            for (int dt = 0; dt < 2; dt++) {
                bf8 vf = *(bf8*)&Vr[(dt * 32 + l31) * 72 + c * 16 + hi * 8];
                o_acc[dt] = __builtin_amdgcn_mfma_f32_32x32x16_bf16(vf, pf[c], o_acc[dt], 0, 0, 0);
            }
        }
        __syncthreads();   // cur^1 staged for all waves; cur fully consumed
        cur ^= 1;
    }

    l_part += __shfl_xor(l_part, 32, 64);
    if (hi == 0) Lw[((size_t)ks * 32 + bh) * 2048 + tok] = l_part;

    size_t pbase = (((size_t)(ks * 32 + bh)) * 2048 + tok) * 64;
    #pragma unroll
    for (int dt = 0; dt < 2; dt++)
    #pragma unroll
    for (int g = 0; g < 4; g++) {
        int d0 = dt * 32 + g * 8 + hi * 4;
        uint2 o;
        o.x = pack2bf_fast(o_acc[dt][g * 4 + 0], o_acc[dt][g * 4 + 1]);
        o.y = pack2bf_fast(o_acc[dt][g * 4 + 2], o_acc[dt][g * 4 + 3]);
        *(uint2*)&Opart[pbase + d0] = o;
    }
}

// ---------------------------------------------------------------------------
// Fused combine + router, runtime split count. Grid 256 x 256.
// ---------------------------------------------------------------------------
__global__ __launch_bounds__(256)
void fuseCR(const ushort_t* __restrict__ Opart, const float* __restrict__ Lw,
            const ushort_t* __restrict__ Wg, const float* __restrict__ br,
            const float* __restrict__ bs, ushort_t* __restrict__ Ob,
            float* __restrict__ G, int splits)
{
    __shared__ ushort_t Obs[16 * 1032];    // 16 tokens x 1024 dims, +8 pad
    __shared__ float rl_s[16][16];         // [head][token]
    __shared__ float Ls[16][21];

    int t = threadIdx.x;
    int tokg0 = blockIdx.x * 16;
    int b = tokg0 >> 11, st0 = tokg0 & 2047;

    // stage per-(head,token) reciprocal denominators (exactly 256 of them)
    {
        int h = t >> 4, tt = t & 15;
        size_t row = (size_t)(b * 16 + h) * 2048 + st0 + tt;
        float l = 0.f;
        #pragma unroll 4
        for (int s = 0; s < splits; s++) l += Lw[(size_t)s * 65536 + row];
        rl_s[h][tt] = 1.f / l;
    }
    __syncthreads();

    // combine: thread t -> token tt = t>>4, dims dc..dc+3 (uint2 per split)
    {
        int tt = t >> 4, dc = (t & 15) * 4;
        #pragma unroll 4
        for (int h = 0; h < 16; h++) {
            size_t rbase = ((size_t)(b * 16 + h) * 2048 + st0 + tt) * 64 + dc;
            float v0 = 0.f, v1 = 0.f, v2 = 0.f, v3 = 0.f;
            #pragma unroll 4
            for (int s = 0; s < splits; s++) {
                uint2 p = *(const uint2*)&Opart[(size_t)s * 4194304 + rbase];
                v0 += bf2f(p.x & 0xffff);
                v1 += bf2f(p.x >> 16);
                v2 += bf2f(p.y & 0xffff);
                v3 += bf2f(p.y >> 16);
            }
            float rl = rl_s[h][tt];
            v0 *= rl; v1 *= rl; v2 *= rl; v3 *= rl;
            uint2 o;
            o.x = pack2bf(v0, v1);
            o.y = pack2bf(v2, v3);
            *(uint2*)&Obs[tt * 1032 + h * 64 + dc] = o;
            *(uint2*)&Ob[((size_t)(tokg0 + tt)) * 1024 + h * 64 + dc] = o;
        }
    }
    __syncthreads();

    // router (wave 0 only): logits[16 tok][17] from LDS
    if (t < 64) {
        int lm = t & 15, quad = t >> 4;
        const ushort_t* b0p = &Wg[(size_t)lm * 1024 + quad * 8];
        const ushort_t* b1p = &Wg[(size_t)(16 + lm) * 1024 + quad * 8];
        f4 acc0 = {}, acc1 = {};
        for (int k0 = 0; k0 < 1024; k0 += 32) {
            bf8 a  = *(const bf8*)&Obs[lm * 1032 + k0 + quad * 8];
            bf8 b0 = *(const bf8*)(b0p + k0);
            bf8 b1 = *(const bf8*)(b1p + k0);
            acc0 = __builtin_amdgcn_mfma_f32_16x16x32_bf16(a, b0, acc0, 0, 0, 0);
            acc1 = __builtin_amdgcn_mfma_f32_16x16x32_bf16(a, b1, acc1, 0, 0, 0);
        }
        #pragma unroll
        for (int i = 0; i < 4; i++) {
            int tl = quad * 4 + i;
            Ls[tl][lm] = acc0[i];
            if (lm == 0) Ls[tl][16] = acc1[i];
        }
        waitl0();   // intra-wave LDS ordering before cross-lane read

        if (t < 16) {
            float v[15];
            float mx = -1e30f;
            #pragma unroll
            for (int c = 0; c < 15; c++) { v[c] = Ls[t][c] + br[c]; mx = fmaxf(mx, v[c]); }
            float sum = 0.f;
            #pragma unroll
            for (int c = 0; c < 15; c++) { v[c] = __expf(v[c] - mx); sum += v[c]; }
            float inv = 1.f / sum;
            float t3 = 0.f;
            for (int r = 0; r < 3; r++) {
                int bi = 0; float bv = -1e30f;
                #pragma unroll
                for (int c = 0; c < 15; c++) if (v[c] > bv) { bv = v[c]; bi = c; }
                t3 += bv; v[bi] = -1e30f;
            }
            t3 *= inv;
            float a0 = Ls[t][15] + bs[0], a1 = Ls[t][16] + bs[1];
            float m2 = fmaxf(a0, a1);
            float e0 = __expf(a0 - m2), e1 = __expf(a1 - m2);
            G[tokg0 + t] = (2.f * e0 + 6.f * e1 * t3) / (e0 + e1);
        }
    }
}

// ---------------------------------------------------------------------------
extern "C" void kernel_launch(void* const* d_in, const int* in_sizes, int n_in,
                              void* d_out, int out_size, void* d_ws, size_t ws_size,
                              hipStream_t stream)
{
    const float* x     = (const float*)d_in[0];
    const float* Wq    = (const float*)d_in[1];
    const float* bq    = (const float*)d_in[2];
    const float* Wk    = (const float*)d_in[3];
    const float* bk    = (const float*)d_in[4];
    const float* Wv    = (const float*)d_in[5];
    const float* bv    = (const float*)d_in[6];
    const float* Wproj = (const float*)d_in[7];
    const float* bproj = (const float*)d_in[8];
    const float* Wr    = (const float*)d_in[9];
    const float* br    = (const float*)d_in[10];
    const float* Ws    = (const float*)d_in[11];
    const float* bs    = (const float*)d_in[12];
    const float* temp  = (const float*)d_in[13];
    const float* emb   = (const float*)d_in[14];

    const int M = 4096, N = 1024, Kd = 1024;

    char* ws = (char*)d_ws;
    ushort_t* Kw    = (ushort_t*)ws;                    //  8 MB [B,H,S,64]
    ushort_t* VTw   = (ushort_t*)(ws + 8388608);        //  8 MB [B,H,64,S]
    ushort_t* Qb    = (ushort_t*)(ws + 16777216);       //  8 MB Q; Ob after attn
    ushort_t* Wtp   = (ushort_t*)(ws + 25165824);       //  2 MB Wproj^T
    float*    Gw    = (float*)(ws + 27262976);          // 16 KB
    ushort_t* Wg    = (ushort_t*)(ws + 27279360);       // 64 KB
    float*    Lw    = (float*)(ws + 27344896);          // 512 KB [2][32][2048]
    ushort_t* Wt3   = (ushort_t*)(ws + 27869184);       //  6 MB (dead after QKV)
    ushort_t* Opart = (ushort_t*)(ws + 27869184);       // 16 MB, overlays Wt3+xb
    ushort_t* xb    = (ushort_t*)(ws + 34160640);       //  8 MB (dead after QKV)
    ushort_t* Ob    = Qb;                               // fuseCR writes over Q

    // SK fixed at 2: R12 measured SK=4 as occupancy-neutral and
    // duration-neutral for attn (+3us in fuseCR) -> attn is not TLP-limited.
    const int SK = 2;

    prep<<<8320, 256, 0, stream>>>(x, xb, Wr, Ws, Wg, Wq, Wk, Wv, Wproj,
        Wt3, Wt3 + 1048576, Wt3 + 2097152, Wtp);

    gemmQKV<<<dim3(32, 48), 256, 0, stream>>>(xb, Wt3, bq, bk, bv,
        Qb, Kw, VTw, temp, emb);

    attn<<<512 * SK, 256, 0, stream>>>(Qb, Kw, VTw, Opart, Lw, 2048 / SK);

    fuseCR<<<256, 256, 0, stream>>>(Opart, Lw, Wg, br, bs, Ob, Gw, SK);

    gemmP<<<dim3(64, 8), 256, 0, stream>>>(Ob, Wtp, bproj, Gw, (float*)d_out, M, N, Kd);
}